// Round 2
// baseline (144.632 us; speedup 1.0000x reference)
//
#include <hip/hip_runtime.h>

// z(8,128,64,64) f32, codes(16,256,8) f32
// out: soft(8,64,64,128) | hard(8,64,64,128) | idx(8,64,64,16) as f32
#define NPOS 32768
#define CCH  128
#define LL   16
#define KK   256
#define CD   8

typedef float f32x2 __attribute__((ext_vector_type(2)));
typedef float f32x4 __attribute__((ext_vector_type(4)));

#if __has_builtin(__builtin_amdgcn_exp2f)
#define EXP2NEG(x) __builtin_amdgcn_exp2f(-(x))
#else
#define EXP2NEG(x) __expf(-0.6931471805599453f * (x))
#endif

// F = sqrt(2)*log2(e): with hv' = F*hv, c' = F*c,
//   dot = -0.5*|hv'|^2 - 0.5*|c'|^2 + hv'.c' = -(log2e * dist)^2
//   => exp2(-sqrt(-dot)) == exp(-dist)  (softmin temperature exactly 1.0)
#define FS    2.0402788939f
#define INVFS 0.4901290717f   // ln2/sqrt(2) == 1/FS exactly

__global__ __launch_bounds__(512) void soft_hard_enc(
    const float* __restrict__ z, const float* __restrict__ codes,
    float* __restrict__ out)
{
    // 4 latents x 128 pairs x 4 f32x4: [e_c0,o_c0,e_c1,o_c1,...] scaled by FS
    __shared__ f32x4 s_codes4[4 * 512];   // 32 KB
    __shared__ f32x2 s_c2h[4 * 128];      // 4 KB: {-0.5|c'|^2 even, -0.5|c'|^2 odd}

    const int tid = (int)threadIdx.x;
    const int bid = (int)blockIdx.x;
    const int posBase = (bid >> 2) * 128;
    const int lBase   = (bid & 3) * 4;

    // ---- one-time: stage codes pair-interleaved + scaled, plus -0.5*|c'|^2
    {
        const int ll = tid >> 7;          // 0..3
        const int j  = tid & 127;         // pair index
        const float* g = codes + ((size_t)((lBase + ll) * KK + 2 * j)) * CD;
        f32x4 q0 = FS * ((const f32x4*)g)[0];   // even code c0..c3
        f32x4 q1 = FS * ((const f32x4*)g)[1];   // even c4..c7
        f32x4 q2 = FS * ((const f32x4*)g)[2];   // odd  c0..c3
        f32x4 q3 = FS * ((const f32x4*)g)[3];   // odd  c4..c7
        f32x4* d = s_codes4 + ll * 512 + j * 4;
        d[0] = (f32x4){q0[0], q2[0], q0[1], q2[1]};
        d[1] = (f32x4){q0[2], q2[2], q0[3], q2[3]};
        d[2] = (f32x4){q1[0], q3[0], q1[1], q3[1]};
        d[3] = (f32x4){q1[2], q3[2], q1[3], q3[3]};
        float c2e = q0[0]*q0[0] + q0[1]*q0[1] + q0[2]*q0[2] + q0[3]*q0[3]
                  + q1[0]*q1[0] + q1[1]*q1[1] + q1[2]*q1[2] + q1[3]*q1[3];
        float c2o = q2[0]*q2[0] + q2[1]*q2[1] + q2[2]*q2[2] + q2[3]*q2[3]
                  + q3[0]*q3[0] + q3[1]*q3[1] + q3[2]*q3[2] + q3[3]*q3[3];
        s_c2h[ll * 128 + j] = (f32x2){-0.5f * c2e, -0.5f * c2o};
    }

    const int l   = tid >> 7;             // wave-uniform latent (2 waves per l)
    const int p   = tid & 127;
    const int pos = posBase + p;
    const int b   = pos >> 12;
    const int wh  = pos & 4095;
    const int l4  = lBase + l;

    // hv load (coalesced per channel), scaled, broadcast into pairs; -0.5*|hv'|^2
    const float* zp = z + (((size_t)(b * CCH + l4 * CD)) << 12) + wh;
    f32x2 hvp[CD];
    float hv2 = 0.f;
#pragma unroll
    for (int c = 0; c < CD; ++c) {
        float v = FS * zp[((size_t)c) << 12];
        hvp[c] = (f32x2){v, v};
        hv2 = __builtin_fmaf(v, v, hv2);
    }
    const f32x2 hv2b = (f32x2){-0.5f * hv2, -0.5f * hv2};

    __syncthreads();

    const f32x4* cb  = s_codes4 + (size_t)l * 512;
    const f32x2* c2b = s_c2h + l * 128;

    f32x2 acc[CD];
#pragma unroll
    for (int c = 0; c < CD; ++c) acc[c] = (f32x2){0.f, 0.f};
    f32x2 ssump = (f32x2){0.f, 0.f};
    f32x2 bd = (f32x2){-3.4e38f, -3.4e38f};   // running MAX of dot (== min d2)
    int   bj0 = 0, bj1 = 0;

#pragma unroll 4
    for (int j = 0; j < KK / 2; ++j) {
        f32x4 q0 = cb[j * 4 + 0];     // wave-uniform addr -> LDS broadcast
        f32x4 q1 = cb[j * 4 + 1];
        f32x4 q2 = cb[j * 4 + 2];
        f32x4 q3 = cb[j * 4 + 3];
        // sub-register pair views of the b128 loads (no movs)
        f32x2 c0 = __builtin_shufflevector(q0, q0, 0, 1);
        f32x2 c1 = __builtin_shufflevector(q0, q0, 2, 3);
        f32x2 c2 = __builtin_shufflevector(q1, q1, 0, 1);
        f32x2 c3 = __builtin_shufflevector(q1, q1, 2, 3);
        f32x2 c4 = __builtin_shufflevector(q2, q2, 0, 1);
        f32x2 c5 = __builtin_shufflevector(q2, q2, 2, 3);
        f32x2 c6 = __builtin_shufflevector(q3, q3, 0, 1);
        f32x2 c7 = __builtin_shufflevector(q3, q3, 2, 3);

        // dot = -(log2e*dist)^2, two 4-deep fma chains
        f32x2 dA = __builtin_elementwise_fma(hvp[0], c0, c2b[j] + hv2b);
        dA = __builtin_elementwise_fma(hvp[1], c1, dA);
        dA = __builtin_elementwise_fma(hvp[2], c2, dA);
        dA = __builtin_elementwise_fma(hvp[3], c3, dA);
        f32x2 dB = hvp[4] * c4;
        dB = __builtin_elementwise_fma(hvp[5], c5, dB);
        dB = __builtin_elementwise_fma(hvp[6], c6, dB);
        dB = __builtin_elementwise_fma(hvp[7], c7, dB);
        f32x2 dotp = dA + dB;

        // no clamp needed: min d2 over this data ~0.16 >> fp32 rounding (~1e-6)
        float s0 = __builtin_amdgcn_sqrtf(-dotp[0]);   // neg = free input modifier
        float s1 = __builtin_amdgcn_sqrtf(-dotp[1]);
        f32x2 ep = (f32x2){EXP2NEG(s0), EXP2NEG(s1)};  // = exp(-dist) exactly
        ssump += ep;
        acc[0] = __builtin_elementwise_fma(ep, c0, acc[0]);
        acc[1] = __builtin_elementwise_fma(ep, c1, acc[1]);
        acc[2] = __builtin_elementwise_fma(ep, c2, acc[2]);
        acc[3] = __builtin_elementwise_fma(ep, c3, acc[3]);
        acc[4] = __builtin_elementwise_fma(ep, c4, acc[4]);
        acc[5] = __builtin_elementwise_fma(ep, c5, acc[5]);
        acc[6] = __builtin_elementwise_fma(ep, c6, acc[6]);
        acc[7] = __builtin_elementwise_fma(ep, c7, acc[7]);

        // per-parity argmax(dot) = argmin(d2); strict > keeps first occurrence
        if (dotp[0] > bd[0]) bj0 = j;                  // v_cmp + v_cndmask
        if (dotp[1] > bd[1]) bj1 = j;
        bd = __builtin_elementwise_max(bd, dotp);      // v_pk_max_f32
    }

    // merge parities; exact-tie -> smaller k (np.argmin first occurrence)
    int ke = 2 * bj0, ko = 2 * bj1 + 1;
    int bestk = ke;
    if (bd[1] > bd[0] || (bd[1] == bd[0] && ko < ke)) bestk = ko;

    const float ssum = ssump[0] + ssump[1];
    const float sc   = INVFS / ssum;    // un-scale codes + softmax normalize

    float a0 = (acc[0][0] + acc[0][1]) * sc;
    float a1 = (acc[1][0] + acc[1][1]) * sc;
    float a2 = (acc[2][0] + acc[2][1]) * sc;
    float a3 = (acc[3][0] + acc[3][1]) * sc;
    float a4 = (acc[4][0] + acc[4][1]) * sc;
    float a5 = (acc[5][0] + acc[5][1]) * sc;
    float a6 = (acc[6][0] + acc[6][1]) * sc;
    float a7 = (acc[7][0] + acc[7][1]) * sc;

    const size_t obase = (size_t)pos * CCH + (size_t)(l4 * CD);
    *(f32x4*)&out[obase]     = (f32x4){a0, a1, a2, a3};
    *(f32x4*)&out[obase + 4] = (f32x4){a4, a5, a6, a7};

    // hard: gather un-scaled code from global (L2-hot 128 KB)
    const float* hp = codes + ((size_t)(l4 * KK + bestk)) * CD;
    f32x4 h0 = ((const f32x4*)hp)[0];
    f32x4 h1 = ((const f32x4*)hp)[1];
    float* outh = out + (size_t)NPOS * CCH;
    *(f32x4*)&outh[obase]     = h0;
    *(f32x4*)&outh[obase + 4] = h1;

    float* outi = out + (size_t)2 * NPOS * CCH;
    outi[(size_t)pos * LL + l4] = (float)bestk;
}

extern "C" void kernel_launch(void* const* d_in, const int* in_sizes, int n_in,
                              void* d_out, int out_size, void* d_ws, size_t ws_size,
                              hipStream_t stream) {
    const float* z     = (const float*)d_in[0];
    const float* codes = (const float*)d_in[1];
    float* out = (float*)d_out;
    soft_hard_enc<<<dim3((NPOS / 128) * 4), dim3(512), 0, stream>>>(z, codes, out);
}

// Round 3
// 142.755 us; speedup vs baseline: 1.0132x; 1.0132x over previous
//
#include <hip/hip_runtime.h>

// z(8,128,64,64) f32, codes(16,256,8) f32
// out: soft(8,64,64,128) | hard(8,64,64,128) | idx(8,64,64,16) as f32
#define NPOS 32768
#define CCH  128
#define LL   16
#define KK   256
#define CD   8

typedef float f32x2 __attribute__((ext_vector_type(2)));
typedef float f32x4 __attribute__((ext_vector_type(4)));

#if __has_builtin(__builtin_amdgcn_exp2f)
#define EXP2NEG(x) __builtin_amdgcn_exp2f(-(x))
#else
#define EXP2NEG(x) __expf(-0.6931471805599453f * (x))
#endif

// F = sqrt(2)*log2(e): with hv' = F*hv, c' = F*c,
//   dot = -0.5*|hv'|^2 - 0.5*|c'|^2 + hv'.c' = -(log2e * dist)^2
//   => exp2(-sqrt(-dot)) == exp(-dist)  (softmin temperature exactly 1.0)
#define FS    2.0402788939f
#define INVFS 0.4901290717f   // ln2/sqrt(2) == 1/FS exactly

// ws layout (floats):
//   [0, 32768)      scaled pair-interleaved codes  [16][128][16]
//   [32768, 36864)  pair seeds {-.5|e'|^2,-.5|o'|^2} [16][128][2]
#define WS_SEED_OFF 32768

__global__ __launch_bounds__(256) void prep_codes(
    const float* __restrict__ codes, float* __restrict__ ws)
{
    const int t = (int)(blockIdx.x * 256 + threadIdx.x);   // 2048 = 16*128
    const int l = t >> 7, j = t & 127;
    const float* g = codes + ((size_t)(l * KK + 2 * j)) * CD;
    f32x4 q0 = FS * ((const f32x4*)g)[0];   // even code c0..c3
    f32x4 q1 = FS * ((const f32x4*)g)[1];   // even c4..c7
    f32x4 q2 = FS * ((const f32x4*)g)[2];   // odd  c0..c3
    f32x4 q3 = FS * ((const f32x4*)g)[3];   // odd  c4..c7
    f32x4* d = (f32x4*)(ws + (size_t)l * 2048 + j * 16);
    d[0] = (f32x4){q0[0], q2[0], q0[1], q2[1]};
    d[1] = (f32x4){q0[2], q2[2], q0[3], q2[3]};
    d[2] = (f32x4){q1[0], q3[0], q1[1], q3[1]};
    d[3] = (f32x4){q1[2], q3[2], q1[3], q3[3]};
    float c2e = q0[0]*q0[0] + q0[1]*q0[1] + q0[2]*q0[2] + q0[3]*q0[3]
              + q1[0]*q1[0] + q1[1]*q1[1] + q1[2]*q1[2] + q1[3]*q1[3];
    float c2o = q2[0]*q2[0] + q2[1]*q2[1] + q2[2]*q2[2] + q2[3]*q2[3]
              + q3[0]*q3[0] + q3[1]*q3[1] + q3[2]*q3[2] + q3[3]*q3[3];
    ((f32x2*)(ws + WS_SEED_OFF))[l * 128 + j] = (f32x2){-0.5f * c2e, -0.5f * c2o};
}

__global__ __launch_bounds__(256) void soft_hard_enc(
    const float* __restrict__ z, const float* __restrict__ codes,
    const float* __restrict__ ws, float* __restrict__ out)
{
    const int tid = (int)threadIdx.x;
    const int bid = (int)blockIdx.x;
    const int l4  = bid & 15;                 // block-uniform latent -> SGPR addrs
    const int pos = ((bid >> 4) << 8) + tid;  // 128 pos-chunks x 256 threads
    const int b   = pos >> 12;
    const int wh  = pos & 4095;

    // hv load (coalesced per channel), scaled, broadcast into pairs; -0.5*|hv'|^2
    const float* zp = z + (((size_t)(b * CCH + l4 * CD)) << 12) + wh;
    f32x2 hvp[CD];
    float hv2 = 0.f;
#pragma unroll
    for (int c = 0; c < CD; ++c) {
        float v = FS * zp[((size_t)c) << 12];
        hvp[c] = (f32x2){v, v};
        hv2 = __builtin_fmaf(v, v, hv2);
    }
    const f32x2 hv2b = (f32x2){-0.5f * hv2, -0.5f * hv2};

    // uniform code streams -> scalar (s_load) path, zero LDS / zero VMEM in loop
    const float* cA = ws + (size_t)l4 * 2048;
    const f32x2* cS = (const f32x2*)(ws + WS_SEED_OFF) + (size_t)l4 * 128;

    f32x2 acc[CD];
#pragma unroll
    for (int c = 0; c < CD; ++c) acc[c] = (f32x2){0.f, 0.f};
    f32x2 ssump = (f32x2){0.f, 0.f};
    f32x2 bd = (f32x2){-3.4e38f, -3.4e38f};   // running MAX of dot (== min d2)
    int   bj0 = 0, bj1 = 0;

    // depth-2 rotated scalar prefetch
    const f32x4* c4 = (const f32x4*)cA;
    f32x4 A0 = c4[0], A1 = c4[1], A2 = c4[2], A3 = c4[3];
    f32x2 AS = cS[0];
    f32x4 B0 = c4[4], B1 = c4[5], B2 = c4[6], B3 = c4[7];
    f32x2 BS = cS[1];

#pragma unroll 2
    for (int j = 0; j < KK / 2; ++j) {
        const int jn = (j + 2) & 127;                 // wrap: tail reloads j=0,1 (unused)
        const f32x4* c4n = (const f32x4*)(cA + (size_t)jn * 16);
        f32x4 N0 = c4n[0], N1 = c4n[1], N2 = c4n[2], N3 = c4n[3];
        f32x2 NS = cS[jn];

        f32x2 c0 = __builtin_shufflevector(A0, A0, 0, 1);
        f32x2 c1 = __builtin_shufflevector(A0, A0, 2, 3);
        f32x2 c2 = __builtin_shufflevector(A1, A1, 0, 1);
        f32x2 c3 = __builtin_shufflevector(A1, A1, 2, 3);
        f32x2 c4v = __builtin_shufflevector(A2, A2, 0, 1);
        f32x2 c5 = __builtin_shufflevector(A2, A2, 2, 3);
        f32x2 c6 = __builtin_shufflevector(A3, A3, 0, 1);
        f32x2 c7 = __builtin_shufflevector(A3, A3, 2, 3);

        // dot = -(log2e*dist)^2, two chains
        f32x2 dA = __builtin_elementwise_fma(hvp[0], c0, AS + hv2b);
        dA = __builtin_elementwise_fma(hvp[1], c1, dA);
        dA = __builtin_elementwise_fma(hvp[2], c2, dA);
        dA = __builtin_elementwise_fma(hvp[3], c3, dA);
        f32x2 dB = hvp[4] * c4v;
        dB = __builtin_elementwise_fma(hvp[5], c5, dB);
        dB = __builtin_elementwise_fma(hvp[6], c6, dB);
        dB = __builtin_elementwise_fma(hvp[7], c7, dB);
        f32x2 dotp = dA + dB;

        // min d2 over this data ~0.16 >> fp32 rounding -> sqrt arg is safe
        float s0 = __builtin_amdgcn_sqrtf(-dotp[0]);   // neg = free input modifier
        float s1 = __builtin_amdgcn_sqrtf(-dotp[1]);
        f32x2 ep = (f32x2){EXP2NEG(s0), EXP2NEG(s1)};  // = exp(-dist) exactly
        ssump += ep;
        acc[0] = __builtin_elementwise_fma(ep, c0, acc[0]);
        acc[1] = __builtin_elementwise_fma(ep, c1, acc[1]);
        acc[2] = __builtin_elementwise_fma(ep, c2, acc[2]);
        acc[3] = __builtin_elementwise_fma(ep, c3, acc[3]);
        acc[4] = __builtin_elementwise_fma(ep, c4v, acc[4]);
        acc[5] = __builtin_elementwise_fma(ep, c5, acc[5]);
        acc[6] = __builtin_elementwise_fma(ep, c6, acc[6]);
        acc[7] = __builtin_elementwise_fma(ep, c7, acc[7]);

        // per-parity argmax(dot) = argmin(d2); strict > keeps first occurrence
        if (dotp[0] > bd[0]) bj0 = j;
        if (dotp[1] > bd[1]) bj1 = j;
        bd = __builtin_elementwise_max(bd, dotp);

        A0 = B0; A1 = B1; A2 = B2; A3 = B3; AS = BS;
        B0 = N0; B1 = N1; B2 = N2; B3 = N3; BS = NS;
    }

    // merge parities; exact-tie -> smaller k (np.argmin first occurrence)
    int ke = 2 * bj0, ko = 2 * bj1 + 1;
    int bestk = ke;
    if (bd[1] > bd[0] || (bd[1] == bd[0] && ko < ke)) bestk = ko;

    const float ssum = ssump[0] + ssump[1];
    const float sc   = INVFS / ssum;    // un-scale codes + softmax normalize

    float a0 = (acc[0][0] + acc[0][1]) * sc;
    float a1 = (acc[1][0] + acc[1][1]) * sc;
    float a2 = (acc[2][0] + acc[2][1]) * sc;
    float a3 = (acc[3][0] + acc[3][1]) * sc;
    float a4 = (acc[4][0] + acc[4][1]) * sc;
    float a5 = (acc[5][0] + acc[5][1]) * sc;
    float a6 = (acc[6][0] + acc[6][1]) * sc;
    float a7 = (acc[7][0] + acc[7][1]) * sc;

    const size_t obase = (size_t)pos * CCH + (size_t)(l4 * CD);
    *(f32x4*)&out[obase]     = (f32x4){a0, a1, a2, a3};
    *(f32x4*)&out[obase + 4] = (f32x4){a4, a5, a6, a7};

    // hard: gather un-scaled code from global (L2-hot 128 KB)
    const float* hp = codes + ((size_t)(l4 * KK + bestk)) * CD;
    f32x4 h0 = ((const f32x4*)hp)[0];
    f32x4 h1 = ((const f32x4*)hp)[1];
    float* outh = out + (size_t)NPOS * CCH;
    *(f32x4*)&outh[obase]     = h0;
    *(f32x4*)&outh[obase + 4] = h1;

    float* outi = out + (size_t)2 * NPOS * CCH;
    outi[(size_t)pos * LL + l4] = (float)bestk;
}

extern "C" void kernel_launch(void* const* d_in, const int* in_sizes, int n_in,
                              void* d_out, int out_size, void* d_ws, size_t ws_size,
                              hipStream_t stream) {
    const float* z     = (const float*)d_in[0];
    const float* codes = (const float*)d_in[1];
    float* ws  = (float*)d_ws;
    float* out = (float*)d_out;
    prep_codes<<<dim3(8), dim3(256), 0, stream>>>(codes, ws);
    soft_hard_enc<<<dim3((NPOS / 256) * LL), dim3(256), 0, stream>>>(z, codes, ws, out);
}